// Round 1
// baseline (232.908 us; speedup 1.0000x reference)
//
#include <hip/hip_runtime.h>

#define DIM 512
#define WAVE 64
#define WPB 4                        // waves per block
#define RPW 4                        // rows per wave (16 lanes per row)
#define BLOCK (WAVE * WPB)
#define ROWS_PER_BLOCK (WPB * RPW)   // 16
#define LPR 16                       // lanes per row
#define EPL (DIM / LPR)              // elems per lane = 32
#define F4PL (EPL / 4)               // float4 per lane = 8

// ds_swizzle BitMode: offset = (xor<<10)|(or<<5)|and. and=0x1f, or=0, xor=m.
// xor in {1,2,4,8} stays within each 16-lane group (and within 32-lane halves,
// which is all ds_swizzle can address) -> 4-stage butterfly per 16-lane row.
#define SWZF(v, m) __int_as_float(__builtin_amdgcn_ds_swizzle(__float_as_int(v), ((m) << 10) | 0x1f))
#define SWZI(v, m) __builtin_amdgcn_ds_swizzle((v), ((m) << 10) | 0x1f)

__global__ __launch_bounds__(BLOCK) void sparsemax_kernel(
    const float* __restrict__ x, float* __restrict__ out, int batch) {
    const int wid  = threadIdx.x >> 6;
    const int lane = threadIdx.x & 63;
    const int g    = lane >> 4;      // which row of this wave's 4
    const int sub  = lane & 15;      // lane within the row
    const int row  = blockIdx.x * ROWS_PER_BLOCK + wid * RPW + g;
    if (row >= batch) return;        // whole 16-lane group exits together

    // ---- load: 8x float4 per lane, stride 16 float4 (256B segments, coalesced)
    const float4* xr = reinterpret_cast<const float4*>(x) + (size_t)row * (DIM / 4);
    float z[EPL];
#pragma unroll
    for (int i = 0; i < F4PL; ++i) {
        float4 v = xr[sub + i * LPR];
        z[4 * i + 0] = v.x; z[4 * i + 1] = v.y;
        z[4 * i + 2] = v.z; z[4 * i + 3] = v.w;
    }

    // ---- row max (per-lane tree, then 4-stage 16-lane butterfly)
    float m = fmaxf(z[0], z[1]);
#pragma unroll
    for (int j = 2; j < EPL; ++j) m = fmaxf(m, z[j]);
    m = fmaxf(m, SWZF(m, 1));
    m = fmaxf(m, SWZF(m, 2));
    m = fmaxf(m, SWZF(m, 4));
    m = fmaxf(m, SWZF(m, 8));

    // ---- Michelot / fixed-point: tau' = (S-1)/K over {z > tau}.
    // tau0 = max-1 is a valid lower bound (p_max <= 1); sets shrink, tau
    // monotone up, finite exact convergence (K stable <=> fixed point).
    // Converged rows recompute a bitwise-identical tau, so running the wave
    // until ALL 4 rows are stable is harmless.
    float tau = m - 1.0f;
    int kprev = 0;
    for (int it = 0; it < 32; ++it) {
        float S = 0.f;
        int   K = 0;
#pragma unroll
        for (int j = 0; j < EPL; ++j) {
            const bool in = z[j] > tau;
            S += in ? z[j] : 0.f;
            K += in ? 1 : 0;
        }
        // two independent 4-stage butterflies (S float, K int), interleaved
        // so their LDS latencies overlap
        { float s1 = SWZF(S, 1); int k1 = SWZI(K, 1); S += s1; K += k1; }
        { float s1 = SWZF(S, 2); int k1 = SWZI(K, 2); S += s1; K += k1; }
        { float s1 = SWZF(S, 4); int k1 = SWZI(K, 4); S += s1; K += k1; }
        { float s1 = SWZF(S, 8); int k1 = SWZI(K, 8); S += s1; K += k1; }
        if (__all(K == kprev)) break;  // all 4 rows stable -> fixed point
        kprev = K;
        tau = (S - 1.0f) * __builtin_amdgcn_rcpf((float)K);  // K >= 1 always
    }

    // ---- epilogue: out = max(0, z - tau)
    float4* orow = reinterpret_cast<float4*>(out) + (size_t)row * (DIM / 4);
#pragma unroll
    for (int i = 0; i < F4PL; ++i) {
        float4 v;
        v.x = fmaxf(0.f, z[4 * i + 0] - tau);
        v.y = fmaxf(0.f, z[4 * i + 1] - tau);
        v.z = fmaxf(0.f, z[4 * i + 2] - tau);
        v.w = fmaxf(0.f, z[4 * i + 3] - tau);
        orow[sub + i * LPR] = v;
    }
}

extern "C" void kernel_launch(void* const* d_in, const int* in_sizes, int n_in,
                              void* d_out, int out_size, void* d_ws, size_t ws_size,
                              hipStream_t stream) {
    const float* x = (const float*)d_in[0];
    float* out     = (float*)d_out;
    const int batch = in_sizes[0] / DIM;  // 65536
    const int grid  = (batch + ROWS_PER_BLOCK - 1) / ROWS_PER_BLOCK;
    sparsemax_kernel<<<grid, BLOCK, 0, stream>>>(x, out, batch);
}